// Round 3
// baseline (476.967 us; speedup 1.0000x reference)
//
#include <hip/hip_runtime.h>
#include <math.h>

#define N_NODES 100000
#define N_EDGES 1600000
#define HID 128
#define OUTD 47
#define OSTR 48

#define NPB 128                       // nodes per fine bucket
#define NB 782                        // ceil(100000/128)
#define BCAP 2560                     // record capacity per fine bucket (mean 2046, max ~2300)
#define CHUNK 2048                    // edges per phase-A block
#define NCHB 782                      // phase-A binning blocks
#define CWB 64                        // convw blocks appended to binA grid

typedef short bf16x8 __attribute__((ext_vector_type(8)));
typedef float f32x4 __attribute__((ext_vector_type(4)));

__device__ inline unsigned short f2bf(float x) {
    union { float f; unsigned int u; } v; v.f = x;
    unsigned int r = v.u + 0x7fffu + ((v.u >> 16) & 1u);   // RNE
    return (unsigned short)(r >> 16);
}
__device__ inline float bf_lo(unsigned int u) { return __uint_as_float(u << 16); }
__device__ inline float bf_hi(unsigned int u) { return __uint_as_float(u & 0xffff0000u); }

// packed RNE f32x2 -> bf16x2 (bit-identical to f2bf pair; single VALU op)
__device__ inline unsigned int cvt_pk_bf16(float lo, float hi) {
    unsigned int r;
    asm("v_cvt_pk_bf16_f32 %0, %1, %2" : "=v"(r) : "v"(lo), "v"(hi));
    return r;
}

// src-chunk for gather locality: 16 chunks of 6250 nodes
__device__ inline unsigned int src_chunk(unsigned int s) {
    return (s * 42950u) >> 28;   // == s / 6250 for s < 100000
}

// ---------------- Phase A: bin edges by dst fine-bucket + (appended blocks) weight convert ----------------

__global__ __launch_bounds__(256) void binA_k(
    const int* __restrict__ src, const int* __restrict__ dst,
    int* __restrict__ gcur, unsigned int* __restrict__ binned,
    const float* __restrict__ W0, const float* __restrict__ W1, const float* __restrict__ W2,
    unsigned short* __restrict__ Wt0, unsigned short* __restrict__ Wt1,
    unsigned short* __restrict__ Wt2)
{
    __shared__ unsigned int sortedL[CHUNK];       // 8 KB
    __shared__ unsigned short bucketOf[CHUNK];    // 4 KB
    __shared__ int cntL[NB];
    __shared__ int excL[NB];
    __shared__ int curL[NB];
    __shared__ int gposL[NB];
    __shared__ int partial[256];

    int t = threadIdx.x;

    if (blockIdx.x >= NCHB) {
        // weight-convert tail blocks
        int i = (blockIdx.x - NCHB) * 256 + t;
        if (i < 16384) {
            int n = i >> 7, k = i & 127;
            Wt0[i] = f2bf(W0[k * 128 + n]);
            Wt1[i] = f2bf(W1[k * 128 + n]);
        }
        if (i < 48 * 128) {
            int n = i >> 7, k = i & 127;
            Wt2[i] = (n < OUTD) ? f2bf(W2[k * OUTD + n]) : (unsigned short)0;
        }
        return;
    }

    int e0 = blockIdx.x * CHUNK;

    for (int i = t; i < NB; i += 256) cntL[i] = 0;
    __syncthreads();

    for (int i = t; i < CHUNK; i += 256) {
        int e = e0 + i;
        if (e < N_EDGES) atomicAdd(&cntL[dst[e] >> 7], 1);
    }
    __syncthreads();

    // exclusive scan of cntL[NB]
    int b4 = t * 4;
    int c0 = (b4 + 0 < NB) ? cntL[b4 + 0] : 0;
    int c1 = (b4 + 1 < NB) ? cntL[b4 + 1] : 0;
    int c2 = (b4 + 2 < NB) ? cntL[b4 + 2] : 0;
    int c3 = (b4 + 3 < NB) ? cntL[b4 + 3] : 0;
    int lsum = c0 + c1 + c2 + c3;
    partial[t] = lsum;
    __syncthreads();
    for (int off = 1; off < 256; off <<= 1) {
        int x = (t >= off) ? partial[t - off] : 0;
        __syncthreads();
        partial[t] += x;
        __syncthreads();
    }
    int pbase = partial[t] - lsum;
    if (b4 + 0 < NB) { excL[b4 + 0] = pbase;                curL[b4 + 0] = pbase; }
    if (b4 + 1 < NB) { excL[b4 + 1] = pbase + c0;           curL[b4 + 1] = pbase + c0; }
    if (b4 + 2 < NB) { excL[b4 + 2] = pbase + c0 + c1;      curL[b4 + 2] = pbase + c0 + c1; }
    if (b4 + 3 < NB) { excL[b4 + 3] = pbase + c0 + c1 + c2; curL[b4 + 3] = pbase + c0 + c1 + c2; }
    __syncthreads();

    int tot = partial[255];

    for (int i = t; i < CHUNK; i += 256) {
        int e = e0 + i;
        if (e < N_EDGES) {
            int d = dst[e];
            int s = src[e];
            int bkt = d >> 7;
            int pos = atomicAdd(&curL[bkt], 1);
            sortedL[pos] = ((unsigned int)s << 7) | (unsigned int)(d & 127);
            bucketOf[pos] = (unsigned short)bkt;
        }
    }
    __syncthreads();

    for (int b = t; b < NB; b += 256) {
        int c = cntL[b];
        gposL[b] = c ? atomicAdd(&gcur[b], c) : 0;
    }
    __syncthreads();

    for (int i = t; i < tot; i += 256) {
        unsigned int r = sortedL[i];
        int bkt = bucketOf[i];
        binned[(size_t)bkt * BCAP + gposL[bkt] + (i - excL[bkt])] = r;
    }
}

// ---------------- Phase B: per-fine-bucket CSR finalize into fixed regions ----------------

__global__ __launch_bounds__(256) void binB_k(
    const unsigned int* __restrict__ binned, const int* __restrict__ gcur,
    int2* __restrict__ rowse, float* __restrict__ dinv, int* __restrict__ colv)
{
    __shared__ unsigned int recL[BCAP];   // 10 KB
    __shared__ int colL[BCAP];            // 10 KB
    __shared__ int hist[2048];            // 8 KB: key = (localnode<<4) | src_chunk
    __shared__ int partial[256];

    int b = blockIdx.x, t = threadIdx.x;
    int cnt = gcur[b];
    int base = b * BCAP;
    const unsigned int* rp = binned + (size_t)b * BCAP;

    for (int i = t; i < 2048; i += 256) hist[i] = 0;
    __syncthreads();

    for (int i = t; i < cnt; i += 256) {
        unsigned int r = rp[i];
        recL[i] = r;
        unsigned int key = ((r & 127u) << 4) | src_chunk(r >> 7);
        atomicAdd(&hist[key], 1);
    }
    __syncthreads();

    // in-place exclusive scan of hist[2048]
    int base8 = t * 8;
    int v[8], lsum = 0;
#pragma unroll
    for (int j = 0; j < 8; j++) { v[j] = hist[base8 + j]; lsum += v[j]; }
    partial[t] = lsum;
    __syncthreads();
    for (int off = 1; off < 256; off <<= 1) {
        int x = (t >= off) ? partial[t - off] : 0;
        __syncthreads();
        partial[t] += x;
        __syncthreads();
    }
    int run = partial[t] - lsum;
#pragma unroll
    for (int j = 0; j < 8; j++) { hist[base8 + j] = run; run += v[j]; }
    __syncthreads();

    if (t < NPB) {
        int node = b * NPB + t;
        if (node < N_NODES) {
            int start = hist[t << 4];
            int end = (t < NPB - 1) ? hist[(t + 1) << 4] : cnt;
            rowse[node] = make_int2(base + start, base + end);
            dinv[node] = rsqrtf((float)(end - start + 1));   // +1 self-loop
        }
    }
    __syncthreads();

    for (int i = t; i < cnt; i += 256) {
        unsigned int r = recL[i];
        unsigned int key = ((r & 127u) << 4) | src_chunk(r >> 7);
        int pos = atomicAdd(&hist[key], 1);
        colL[pos] = (int)(r >> 7);
    }
    __syncthreads();
    for (int i = t; i < cnt; i += 256) colv[base + i] = colL[i];
}

// ---------------- MFMA GEMM (M x 128 @ 128 x N), fused BN-final+BN-apply+ReLU, dinv prescale ----------------

template <int ABF16, int MODE, int NT, int OBF16>
__global__ __launch_bounds__(256) void gemm_k(
    const void* __restrict__ Ap, const unsigned short* __restrict__ Wt,
    const float* __restrict__ bnSum, const float* __restrict__ bnSq,
    const float* __restrict__ gam, const float* __restrict__ bet,
    const float* __restrict__ dinv, void* __restrict__ Outp,
    int ncols, int ostride)
{
    __shared__ unsigned short WtL[NT * 16][136];
    __shared__ float sS[128], sT[128];

    int t = threadIdx.x;
    if (MODE) {
        if (t < 128) {
            float mean = bnSum[t] * (1.0f / N_NODES);
            float var = bnSq[t] * (1.0f / N_NODES) - mean * mean;
            float inv = rsqrtf(var + 1e-5f);
            float s = gam[t] * inv;
            sS[t] = s;
            sT[t] = bet[t] - mean * s;
        }
    }

    const int TOT = NT * 16 * 128;
    for (int e = t * 8; e < TOT; e += 256 * 8) {
        int n = e >> 7, k = e & 127;
        uint4 v = *(const uint4*)(Wt + e);
        *(uint4*)&WtL[n][k] = v;
    }
    __syncthreads();

    int wave = t >> 6, lane = t & 63;
    int quad = lane >> 4, m16 = lane & 15;
    int rbase = blockIdx.x * 128 + wave * 32;

    f32x4 acc[2][NT];
#pragma unroll
    for (int rt = 0; rt < 2; rt++)
#pragma unroll
        for (int ct = 0; ct < NT; ct++) acc[rt][ct] = (f32x4){0.f, 0.f, 0.f, 0.f};

#pragma unroll
    for (int kc = 0; kc < 4; kc++) {
        int kb = kc * 32 + quad * 8;
        bf16x8 afrag[2];
#pragma unroll
        for (int rt = 0; rt < 2; rt++) {
            int row = rbase + rt * 16 + m16;
            bool rv = (row < N_NODES);
            if (ABF16) {
                uint4 v = make_uint4(0, 0, 0, 0);
                if (rv) v = *(const uint4*)((const unsigned short*)Ap + (size_t)row * 128 + kb);
                if (MODE) {
                    unsigned int uu[4] = {v.x, v.y, v.z, v.w};
                    unsigned short* fp = (unsigned short*)&afrag[rt];
#pragma unroll
                    for (int i = 0; i < 4; i++) {
                        int k0 = kb + 2 * i;
                        float lo = fmaxf(bf_lo(uu[i]) * sS[k0] + sT[k0], 0.f);
                        float hi = fmaxf(bf_hi(uu[i]) * sS[k0 + 1] + sT[k0 + 1], 0.f);
                        fp[2 * i] = f2bf(lo);
                        fp[2 * i + 1] = f2bf(hi);
                    }
                } else {
                    afrag[rt] = *(bf16x8*)&v;
                }
            } else {
                const float* ap = (const float*)Ap + (size_t)row * 128 + kb;
                float4 f0 = make_float4(0.f, 0.f, 0.f, 0.f), f1 = f0;
                if (rv) { f0 = *(const float4*)ap; f1 = *(const float4*)(ap + 4); }
                unsigned short* fp = (unsigned short*)&afrag[rt];
                fp[0] = f2bf(f0.x); fp[1] = f2bf(f0.y); fp[2] = f2bf(f0.z); fp[3] = f2bf(f0.w);
                fp[4] = f2bf(f1.x); fp[5] = f2bf(f1.y); fp[6] = f2bf(f1.z); fp[7] = f2bf(f1.w);
            }
        }
#pragma unroll
        for (int ct = 0; ct < NT; ct++) {
            bf16x8 bfrag = *(bf16x8*)&WtL[ct * 16 + m16][kb];
#pragma unroll
            for (int rt = 0; rt < 2; rt++)
                acc[rt][ct] = __builtin_amdgcn_mfma_f32_16x16x32_bf16(
                    afrag[rt], bfrag, acc[rt][ct], 0, 0, 0);
        }
    }

#pragma unroll
    for (int rt = 0; rt < 2; rt++)
#pragma unroll
        for (int r = 0; r < 4; r++) {
            int row = rbase + rt * 16 + quad * 4 + r;
            if (row < N_NODES) {
                float d = dinv[row];
#pragma unroll
                for (int ct = 0; ct < NT; ct++) {
                    int c = ct * 16 + m16;
                    if (c < ncols) {
                        float val = acc[rt][ct][r] * d;
                        if (OBF16)
                            ((unsigned short*)Outp)[(size_t)row * ostride + c] = f2bf(val);
                        else
                            ((float*)Outp)[(size_t)row * ostride + c] = val;
                    }
                }
            }
        }
}

// ---------------- Aggregation: one wave per dst node, quarter-wave per record ----------------
// Wave-uniform control (whole wave walks ONE node's record list); quarters handle records
// 4t+q. Unroll-4 over record groups -> 4 independent uint4 gathers in flight per lane
// (a mean-degree-16 node is exactly one unrolled iteration). Epilogue packs via
// v_cvt_pk_bf16_f32 (bit-identical RNE, 4 ops instead of ~24).

__global__ __launch_bounds__(256) void agg_k(
    const unsigned int* __restrict__ H, const int2* __restrict__ rowse,
    const int* __restrict__ colv, const float* __restrict__ dinv,
    const float* __restrict__ bias, unsigned int* __restrict__ out)
{
    int gw = (blockIdx.x * 256 + threadIdx.x) >> 6;
    int lane = threadIdx.x & 63;
    if (gw >= N_NODES) return;
    int q = lane >> 4;             // quarter id: records 4t+q
    int c = lane & 15;             // uint4 index within row (channels 8c..8c+7)
    int2 se = rowse[gw];
    int rp = se.x, re = se.y;
    const uint4* H4 = (const uint4*)H;   // row = 16 uint4 (256 B)

    float a0 = 0.f, a1 = 0.f, a2 = 0.f, a3 = 0.f;
    float a4 = 0.f, a5 = 0.f, a6 = 0.f, a7 = 0.f;
    if (q == 0) {                  // self-loop (prescaled row)
        uint4 u = H4[(size_t)gw * 16 + c];
        a0 = bf_lo(u.x); a1 = bf_hi(u.x); a2 = bf_lo(u.y); a3 = bf_hi(u.y);
        a4 = bf_lo(u.z); a5 = bf_hi(u.z); a6 = bf_lo(u.w); a7 = bf_hi(u.w);
    }

    for (int j0 = rp; j0 < re; j0 += 64) {
        int idx = (j0 + lane < re) ? colv[j0 + lane] : 0;
        int n = min(64, re - j0);
        int nq = n >> 2;           // complete groups of 4 records
        int t4 = 0;
        for (; t4 + 4 <= nq; t4 += 4) {     // 4 independent gathers in flight
            int s0 = __shfl(idx, 4 * t4 + q);
            int s1 = __shfl(idx, 4 * t4 + 4 + q);
            int s2 = __shfl(idx, 4 * t4 + 8 + q);
            int s3 = __shfl(idx, 4 * t4 + 12 + q);
            uint4 u0 = H4[(size_t)s0 * 16 + c];
            uint4 u1 = H4[(size_t)s1 * 16 + c];
            uint4 u2 = H4[(size_t)s2 * 16 + c];
            uint4 u3 = H4[(size_t)s3 * 16 + c];
            a0 += (bf_lo(u0.x) + bf_lo(u1.x)) + (bf_lo(u2.x) + bf_lo(u3.x));
            a1 += (bf_hi(u0.x) + bf_hi(u1.x)) + (bf_hi(u2.x) + bf_hi(u3.x));
            a2 += (bf_lo(u0.y) + bf_lo(u1.y)) + (bf_lo(u2.y) + bf_lo(u3.y));
            a3 += (bf_hi(u0.y) + bf_hi(u1.y)) + (bf_hi(u2.y) + bf_hi(u3.y));
            a4 += (bf_lo(u0.z) + bf_lo(u1.z)) + (bf_lo(u2.z) + bf_lo(u3.z));
            a5 += (bf_hi(u0.z) + bf_hi(u1.z)) + (bf_hi(u2.z) + bf_hi(u3.z));
            a6 += (bf_lo(u0.w) + bf_lo(u1.w)) + (bf_lo(u2.w) + bf_lo(u3.w));
            a7 += (bf_hi(u0.w) + bf_hi(u1.w)) + (bf_hi(u2.w) + bf_hi(u3.w));
        }
        for (; t4 < nq; t4++) {
            int sa = __shfl(idx, 4 * t4 + q);
            uint4 ua = H4[(size_t)sa * 16 + c];
            a0 += bf_lo(ua.x); a1 += bf_hi(ua.x);
            a2 += bf_lo(ua.y); a3 += bf_hi(ua.y);
            a4 += bf_lo(ua.z); a5 += bf_hi(ua.z);
            a6 += bf_lo(ua.w); a7 += bf_hi(ua.w);
        }
        int rem = n & 3;           // tail records: quarters 0..rem-1
        if (rem) {
            int sa = __shfl(idx, (n - rem) + q);
            if (q < rem) {
                uint4 ua = H4[(size_t)sa * 16 + c];
                a0 += bf_lo(ua.x); a1 += bf_hi(ua.x);
                a2 += bf_lo(ua.y); a3 += bf_hi(ua.y);
                a4 += bf_lo(ua.z); a5 += bf_hi(ua.z);
                a6 += bf_lo(ua.w); a7 += bf_hi(ua.w);
            }
        }
    }

    // combine the four quarter accumulators
    a0 += __shfl_xor(a0, 16); a0 += __shfl_xor(a0, 32);
    a1 += __shfl_xor(a1, 16); a1 += __shfl_xor(a1, 32);
    a2 += __shfl_xor(a2, 16); a2 += __shfl_xor(a2, 32);
    a3 += __shfl_xor(a3, 16); a3 += __shfl_xor(a3, 32);
    a4 += __shfl_xor(a4, 16); a4 += __shfl_xor(a4, 32);
    a5 += __shfl_xor(a5, 16); a5 += __shfl_xor(a5, 32);
    a6 += __shfl_xor(a6, 16); a6 += __shfl_xor(a6, 32);
    a7 += __shfl_xor(a7, 16); a7 += __shfl_xor(a7, 32);

    if (q == 0) {
        float d = dinv[gw];
        float4 ba = ((const float4*)bias)[2 * c];
        float4 bb = ((const float4*)bias)[2 * c + 1];
        uint4 r;
        r.x = cvt_pk_bf16(a0 * d + ba.x, a1 * d + ba.y);
        r.y = cvt_pk_bf16(a2 * d + ba.z, a3 * d + ba.w);
        r.z = cvt_pk_bf16(a4 * d + bb.x, a5 * d + bb.y);
        r.w = cvt_pk_bf16(a6 * d + bb.z, a7 * d + bb.w);
        ((uint4*)out)[(size_t)gw * 16 + c] = r;
    }
}

// ---------------- Final aggregation (bf16 48-stride rows), quarter-wave + log_softmax ----------------

__global__ __launch_bounds__(256) void agg_out_k(
    const unsigned int* __restrict__ H, const int2* __restrict__ rowse,
    const int* __restrict__ colv, const float* __restrict__ dinv,
    const float* __restrict__ b2, float* __restrict__ out)
{
    int gw = (blockIdx.x * 256 + threadIdx.x) >> 6;
    int lane = threadIdx.x & 63;
    if (gw >= N_NODES) return;
    int q = lane >> 4;
    int c = lane & 15;
    bool ld = c < 12;              // 12 uint2 = 48 bf16 per row
    int2 se = rowse[gw];
    int rp = se.x, re = se.y;
    const uint2* H2 = (const uint2*)H;   // row = 12 uint2 (96 B)

    float a0 = 0.f, a1 = 0.f, a2 = 0.f, a3 = 0.f;
    if (q == 0 && ld) {
        uint2 u = H2[(size_t)gw * 12 + c];   // self (prescaled)
        a0 = bf_lo(u.x); a1 = bf_hi(u.x); a2 = bf_lo(u.y); a3 = bf_hi(u.y);
    }

    for (int j0 = rp; j0 < re; j0 += 64) {
        int idx = (j0 + lane < re) ? colv[j0 + lane] : 0;
        int n = min(64, re - j0);
        int nq = n >> 2;
        int t4 = 0;
        for (; t4 + 4 <= nq; t4 += 4) {
            int s0 = __shfl(idx, 4 * t4 + q);
            int s1 = __shfl(idx, 4 * t4 + 4 + q);
            int s2 = __shfl(idx, 4 * t4 + 8 + q);
            int s3 = __shfl(idx, 4 * t4 + 12 + q);
            if (ld) {
                uint2 u0 = H2[(size_t)s0 * 12 + c];
                uint2 u1 = H2[(size_t)s1 * 12 + c];
                uint2 u2 = H2[(size_t)s2 * 12 + c];
                uint2 u3 = H2[(size_t)s3 * 12 + c];
                a0 += (bf_lo(u0.x) + bf_lo(u1.x)) + (bf_lo(u2.x) + bf_lo(u3.x));
                a1 += (bf_hi(u0.x) + bf_hi(u1.x)) + (bf_hi(u2.x) + bf_hi(u3.x));
                a2 += (bf_lo(u0.y) + bf_lo(u1.y)) + (bf_lo(u2.y) + bf_lo(u3.y));
                a3 += (bf_hi(u0.y) + bf_hi(u1.y)) + (bf_hi(u2.y) + bf_hi(u3.y));
            }
        }
        for (; t4 < nq; t4++) {
            int sa = __shfl(idx, 4 * t4 + q);
            if (ld) {
                uint2 ua = H2[(size_t)sa * 12 + c];
                a0 += bf_lo(ua.x); a1 += bf_hi(ua.x);
                a2 += bf_lo(ua.y); a3 += bf_hi(ua.y);
            }
        }
        int rem = n & 3;
        if (rem) {
            int sa = __shfl(idx, (n - rem) + q);
            if (q < rem && ld) {
                uint2 ua = H2[(size_t)sa * 12 + c];
                a0 += bf_lo(ua.x); a1 += bf_hi(ua.x);
                a2 += bf_lo(ua.y); a3 += bf_hi(ua.y);
            }
        }
    }

    a0 += __shfl_xor(a0, 16); a0 += __shfl_xor(a0, 32);
    a1 += __shfl_xor(a1, 16); a1 += __shfl_xor(a1, 32);
    a2 += __shfl_xor(a2, 16); a2 += __shfl_xor(a2, 32);
    a3 += __shfl_xor(a3, 16); a3 += __shfl_xor(a3, 32);

    float d = dinv[gw];
    int ch = c * 4;
    float v0 = -INFINITY, v1 = -INFINITY, v2 = -INFINITY, v3 = -INFINITY;
    if (ld) {
        v0 = a0 * d + b2[ch];
        v1 = a1 * d + b2[ch + 1];
        v2 = a2 * d + b2[ch + 2];
        if (ch + 3 < OUTD) v3 = a3 * d + b2[ch + 3];
    }
    float m = fmaxf(fmaxf(v0, v1), fmaxf(v2, v3));
    m = fmaxf(m, __shfl_xor(m, 1));
    m = fmaxf(m, __shfl_xor(m, 2));
    m = fmaxf(m, __shfl_xor(m, 4));
    m = fmaxf(m, __shfl_xor(m, 8));
    float e = 0.f;
    if (ld) {
        e = __expf(v0 - m) + __expf(v1 - m) + __expf(v2 - m);
        if (ch + 3 < OUTD) e += __expf(v3 - m);
    }
    float sum = e;
    sum += __shfl_xor(sum, 1);
    sum += __shfl_xor(sum, 2);
    sum += __shfl_xor(sum, 4);
    sum += __shfl_xor(sum, 8);
    float ls = logf(sum);
    if (q == 0 && ld) {
        float* op = out + (size_t)gw * OUTD + ch;
        op[0] = v0 - m - ls;
        op[1] = v1 - m - ls;
        op[2] = v2 - m - ls;
        if (ch + 3 < OUTD) op[3] = v3 - m - ls;
    }
}

// ---------------- BatchNorm stats (bf16 input) ----------------

__global__ __launch_bounds__(256) void bnstats_k(const unsigned int* __restrict__ H,
                                                 float* __restrict__ sum,
                                                 float* __restrict__ sq)
{
    __shared__ float2 ls[256], lq[256];
    int t = threadIdx.x;
    int idx = blockIdx.x * 256 + t;
    int stride = gridDim.x * 256;
    float sx = 0.f, sy = 0.f, qx = 0.f, qy = 0.f;
    for (; idx < N_NODES * 64; idx += stride) {
        unsigned int u = H[idx];
        float x = bf_lo(u), y = bf_hi(u);
        sx += x; sy += y; qx += x * x; qy += y * y;
    }
    ls[t] = make_float2(sx, sy);
    lq[t] = make_float2(qx, qy);
    __syncthreads();
    if (t < 64) {
        float2 a = ls[t], b = ls[t + 64], c = ls[t + 128], d = ls[t + 192];
        float2 e = lq[t], f = lq[t + 64], g = lq[t + 128], h = lq[t + 192];
        int c0 = t * 2;
        atomicAdd(&sum[c0],     a.x + b.x + c.x + d.x);
        atomicAdd(&sum[c0 + 1], a.y + b.y + c.y + d.y);
        atomicAdd(&sq[c0],      e.x + f.x + g.x + h.x);
        atomicAdd(&sq[c0 + 1],  e.y + f.y + g.y + h.y);
    }
}

// ---------------- launch ----------------

extern "C" void kernel_launch(void* const* d_in, const int* in_sizes, int n_in,
                              void* d_out, int out_size, void* d_ws, size_t ws_size,
                              hipStream_t stream)
{
    const float* x   = (const float*)d_in[0];
    const int*   ei  = (const int*)d_in[1];
    const float* W0  = (const float*)d_in[2];
    const float* b0  = (const float*)d_in[3];
    const float* W1  = (const float*)d_in[4];
    const float* b1  = (const float*)d_in[5];
    const float* W2  = (const float*)d_in[6];
    const float* b2  = (const float*)d_in[7];
    const float* g0  = (const float*)d_in[8];
    const float* be0 = (const float*)d_in[9];
    const float* g1  = (const float*)d_in[10];
    const float* be1 = (const float*)d_in[11];
    const int* srcv = ei;
    const int* dstv = ei + N_EDGES;

    char* w = (char*)d_ws;
    unsigned int* H0 = (unsigned int*)w;  w += (size_t)N_NODES * 128 * 2;   // bf16 [N][128]
    unsigned int* H1 = (unsigned int*)w;  w += (size_t)N_NODES * 128 * 2;   // bf16 [N][128]
    unsigned int* Hf = (unsigned int*)w;  w += (size_t)N_NODES * OSTR * 2;  // bf16 [N][48]
    unsigned int* binned = (unsigned int*)w; w += (size_t)NB * BCAP * 4;    // 8.0 MB
    int* colv = (int*)w;        w += (size_t)NB * BCAP * 4;                 // 8.0 MB (fixed regions)
    unsigned short* Wt0 = (unsigned short*)w; w += 16384 * 2;
    unsigned short* Wt1 = (unsigned short*)w; w += 16384 * 2;
    unsigned short* Wt2 = (unsigned short*)w; w += 48 * 128 * 2;
    int2* rowse = (int2*)w;     w += (size_t)N_NODES * 8;
    float* dinv = (float*)w;    w += (size_t)N_NODES * 4;
    // single-memset region: gcur (784 ints) + bnS0,bnQ0,bnS1,bnQ1 (512 floats)
    int* gcur = (int*)w;        w += 784 * 4;
    float* bnS0 = (float*)w;    w += 128 * 4;
    float* bnQ0 = (float*)w;    w += 128 * 4;
    float* bnS1 = (float*)w;    w += 128 * 4;
    float* bnQ1 = (float*)w;    w += 128 * 4;

    int gb = (N_NODES + 127) / 128;       // 782
    int ab = (N_NODES * 64 + 255) / 256;  // 25000

    hipMemsetAsync(gcur, 0, (784 + 512) * 4, stream);

    binA_k<<<NCHB + CWB, 256, 0, stream>>>(srcv, dstv, gcur, binned,
                                           W0, W1, W2, Wt0, Wt1, Wt2);
    binB_k<<<NB, 256, 0, stream>>>(binned, gcur, rowse, dinv, colv);

    // Layer 0: x fp32 -> H0 bf16 (dinv-prescaled)
    gemm_k<0, 0, 8, 1><<<gb, 256, 0, stream>>>(x, Wt0, nullptr, nullptr, nullptr, nullptr,
                                               dinv, H0, 128, 128);
    agg_k<<<ab, 256, 0, stream>>>(H0, rowse, colv, dinv, b0, H1);
    bnstats_k<<<512, 256, 0, stream>>>(H1, bnS0, bnQ0);

    // Layer 1: BN-final+BN-apply+ReLU fused into gemm, bf16 MFMA
    gemm_k<1, 1, 8, 1><<<gb, 256, 0, stream>>>(H1, Wt1, bnS0, bnQ0, g0, be0,
                                               dinv, H0, 128, 128);
    agg_k<<<ab, 256, 0, stream>>>(H0, rowse, colv, dinv, b1, H1);
    bnstats_k<<<512, 256, 0, stream>>>(H1, bnS1, bnQ1);

    // Layer 2: 47-wide out (bf16, stride 48) + fused log_softmax aggregation
    gemm_k<1, 1, 3, 1><<<gb, 256, 0, stream>>>(H1, Wt2, bnS1, bnQ1, g1, be1,
                                               dinv, Hf, OUTD, OSTR);
    agg_out_k<<<ab, 256, 0, stream>>>(Hf, rowse, colv, dinv, b2, (float*)d_out);
}

// Round 4
// 411.092 us; speedup vs baseline: 1.1602x; 1.1602x over previous
//
#include <hip/hip_runtime.h>
#include <math.h>

#define N_NODES 100000
#define N_EDGES 1600000
#define HID 128
#define OUTD 47
#define OSTR 48

#define NPB 128                       // nodes per fine bucket
#define NB 782                        // ceil(100000/128)
#define BCAP 2560                     // record capacity per fine bucket (mean 2046, max ~2300)
#define CHUNK 2048                    // edges per phase-A block
#define NCHB 782                      // phase-A binning blocks
#define CWB 64                        // convw blocks appended to binA grid

typedef short bf16x8 __attribute__((ext_vector_type(8)));
typedef float f32x4 __attribute__((ext_vector_type(4)));

__device__ inline unsigned short f2bf(float x) {
    union { float f; unsigned int u; } v; v.f = x;
    unsigned int r = v.u + 0x7fffu + ((v.u >> 16) & 1u);   // RNE
    return (unsigned short)(r >> 16);
}
__device__ inline float bf_lo(unsigned int u) { return __uint_as_float(u << 16); }
__device__ inline float bf_hi(unsigned int u) { return __uint_as_float(u & 0xffff0000u); }

// packed RNE f32x2 -> bf16x2 (bit-identical to f2bf pair; single VALU op)
__device__ inline unsigned int cvt_pk_bf16(float lo, float hi) {
    unsigned int r;
    asm("v_cvt_pk_bf16_f32 %0, %1, %2" : "=v"(r) : "v"(lo), "v"(hi));
    return r;
}

// src-chunk for gather locality: 16 chunks of 6250 nodes
__device__ inline unsigned int src_chunk(unsigned int s) {
    return (s * 42950u) >> 28;   // == s / 6250 for s < 100000
}

// ---------------- Phase A: bin edges by dst fine-bucket + (appended blocks) weight convert ----------------

__global__ __launch_bounds__(256) void binA_k(
    const int* __restrict__ src, const int* __restrict__ dst,
    int* __restrict__ gcur, unsigned int* __restrict__ binned,
    const float* __restrict__ W0, const float* __restrict__ W1, const float* __restrict__ W2,
    unsigned short* __restrict__ Wt0, unsigned short* __restrict__ Wt1,
    unsigned short* __restrict__ Wt2)
{
    __shared__ unsigned int sortedL[CHUNK];       // 8 KB
    __shared__ unsigned short bucketOf[CHUNK];    // 4 KB
    __shared__ int cntL[NB];
    __shared__ int excL[NB];
    __shared__ int curL[NB];
    __shared__ int gposL[NB];
    __shared__ int partial[256];

    int t = threadIdx.x;

    if (blockIdx.x >= NCHB) {
        // weight-convert tail blocks
        int i = (blockIdx.x - NCHB) * 256 + t;
        if (i < 16384) {
            int n = i >> 7, k = i & 127;
            Wt0[i] = f2bf(W0[k * 128 + n]);
            Wt1[i] = f2bf(W1[k * 128 + n]);
        }
        if (i < 48 * 128) {
            int n = i >> 7, k = i & 127;
            Wt2[i] = (n < OUTD) ? f2bf(W2[k * OUTD + n]) : (unsigned short)0;
        }
        return;
    }

    int e0 = blockIdx.x * CHUNK;

    for (int i = t; i < NB; i += 256) cntL[i] = 0;
    __syncthreads();

    for (int i = t; i < CHUNK; i += 256) {
        int e = e0 + i;
        if (e < N_EDGES) atomicAdd(&cntL[dst[e] >> 7], 1);
    }
    __syncthreads();

    // exclusive scan of cntL[NB]
    int b4 = t * 4;
    int c0 = (b4 + 0 < NB) ? cntL[b4 + 0] : 0;
    int c1 = (b4 + 1 < NB) ? cntL[b4 + 1] : 0;
    int c2 = (b4 + 2 < NB) ? cntL[b4 + 2] : 0;
    int c3 = (b4 + 3 < NB) ? cntL[b4 + 3] : 0;
    int lsum = c0 + c1 + c2 + c3;
    partial[t] = lsum;
    __syncthreads();
    for (int off = 1; off < 256; off <<= 1) {
        int x = (t >= off) ? partial[t - off] : 0;
        __syncthreads();
        partial[t] += x;
        __syncthreads();
    }
    int pbase = partial[t] - lsum;
    if (b4 + 0 < NB) { excL[b4 + 0] = pbase;                curL[b4 + 0] = pbase; }
    if (b4 + 1 < NB) { excL[b4 + 1] = pbase + c0;           curL[b4 + 1] = pbase + c0; }
    if (b4 + 2 < NB) { excL[b4 + 2] = pbase + c0 + c1;      curL[b4 + 2] = pbase + c0 + c1; }
    if (b4 + 3 < NB) { excL[b4 + 3] = pbase + c0 + c1 + c2; curL[b4 + 3] = pbase + c0 + c1 + c2; }
    __syncthreads();

    int tot = partial[255];

    for (int i = t; i < CHUNK; i += 256) {
        int e = e0 + i;
        if (e < N_EDGES) {
            int d = dst[e];
            int s = src[e];
            int bkt = d >> 7;
            int pos = atomicAdd(&curL[bkt], 1);
            sortedL[pos] = ((unsigned int)s << 7) | (unsigned int)(d & 127);
            bucketOf[pos] = (unsigned short)bkt;
        }
    }
    __syncthreads();

    for (int b = t; b < NB; b += 256) {
        int c = cntL[b];
        gposL[b] = c ? atomicAdd(&gcur[b], c) : 0;
    }
    __syncthreads();

    for (int i = t; i < tot; i += 256) {
        unsigned int r = sortedL[i];
        int bkt = bucketOf[i];
        binned[(size_t)bkt * BCAP + gposL[bkt] + (i - excL[bkt])] = r;
    }
}

// ---------------- Phase B: per-fine-bucket CSR finalize into fixed regions ----------------

__global__ __launch_bounds__(256) void binB_k(
    const unsigned int* __restrict__ binned, const int* __restrict__ gcur,
    int2* __restrict__ rowse, float* __restrict__ dinv, int* __restrict__ colv)
{
    __shared__ unsigned int recL[BCAP];   // 10 KB
    __shared__ int colL[BCAP];            // 10 KB
    __shared__ int hist[2048];            // 8 KB: key = (localnode<<4) | src_chunk
    __shared__ int partial[256];

    int b = blockIdx.x, t = threadIdx.x;
    int cnt = gcur[b];
    int base = b * BCAP;
    const unsigned int* rp = binned + (size_t)b * BCAP;

    for (int i = t; i < 2048; i += 256) hist[i] = 0;
    __syncthreads();

    for (int i = t; i < cnt; i += 256) {
        unsigned int r = rp[i];
        recL[i] = r;
        unsigned int key = ((r & 127u) << 4) | src_chunk(r >> 7);
        atomicAdd(&hist[key], 1);
    }
    __syncthreads();

    // in-place exclusive scan of hist[2048]
    int base8 = t * 8;
    int v[8], lsum = 0;
#pragma unroll
    for (int j = 0; j < 8; j++) { v[j] = hist[base8 + j]; lsum += v[j]; }
    partial[t] = lsum;
    __syncthreads();
    for (int off = 1; off < 256; off <<= 1) {
        int x = (t >= off) ? partial[t - off] : 0;
        __syncthreads();
        partial[t] += x;
        __syncthreads();
    }
    int run = partial[t] - lsum;
#pragma unroll
    for (int j = 0; j < 8; j++) { hist[base8 + j] = run; run += v[j]; }
    __syncthreads();

    if (t < NPB) {
        int node = b * NPB + t;
        if (node < N_NODES) {
            int start = hist[t << 4];
            int end = (t < NPB - 1) ? hist[(t + 1) << 4] : cnt;
            rowse[node] = make_int2(base + start, base + end);
            dinv[node] = rsqrtf((float)(end - start + 1));   // +1 self-loop
        }
    }
    __syncthreads();

    for (int i = t; i < cnt; i += 256) {
        unsigned int r = recL[i];
        unsigned int key = ((r & 127u) << 4) | src_chunk(r >> 7);
        int pos = atomicAdd(&hist[key], 1);
        colL[pos] = (int)(r >> 7);
    }
    __syncthreads();
    for (int i = t; i < cnt; i += 256) colv[base + i] = colL[i];
}

// ---------------- MFMA GEMM (M x 128 @ 128 x N), fused BN-final+BN-apply+ReLU, dinv prescale ----------------
// All 8 A-tile loads hoisted before the K-loop (1 latency exposure, not 4).
// MODE: BN scale/shift kept as float2 in LDS (one ds_read_b64 per pair); packs via cvt_pk.
// MODE prologue sums 64-sliced BN partials produced by agg_k (bnstats kernel eliminated).

template <int ABF16, int MODE, int NT, int OBF16>
__global__ __launch_bounds__(256) void gemm_k(
    const void* __restrict__ Ap, const unsigned short* __restrict__ Wt,
    const float* __restrict__ bnSum, const float* __restrict__ bnSq,
    const float* __restrict__ gam, const float* __restrict__ bet,
    const float* __restrict__ dinv, void* __restrict__ Outp,
    int ncols, int ostride)
{
    __shared__ unsigned short WtL[NT * 16][136];
    __shared__ float2 sST[128];

    int t = threadIdx.x;
    if (MODE) {
        if (t < 128) {
            float s_ = 0.f, q_ = 0.f;
            for (int sl = 0; sl < 64; sl++) {
                s_ += bnSum[sl * 128 + t];
                q_ += bnSq[sl * 128 + t];
            }
            float mean = s_ * (1.0f / N_NODES);
            float var = q_ * (1.0f / N_NODES) - mean * mean;
            float inv = rsqrtf(var + 1e-5f);
            float s = gam[t] * inv;
            sST[t] = make_float2(s, bet[t] - mean * s);
        }
    }

    const int TOT = NT * 16 * 128;
    for (int e = t * 8; e < TOT; e += 256 * 8) {
        int n = e >> 7, k = e & 127;
        uint4 v = *(const uint4*)(Wt + e);
        *(uint4*)&WtL[n][k] = v;
    }
    __syncthreads();

    int wave = t >> 6, lane = t & 63;
    int quad = lane >> 4, m16 = lane & 15;
    int rbase = blockIdx.x * 128 + wave * 32;

    // ---- hoisted A loads: 8 independent 16B loads per thread ----
    uint4 av[2][4];
#pragma unroll
    for (int rt = 0; rt < 2; rt++) {
        int row = rbase + rt * 16 + m16;
        bool rv = (row < N_NODES);
        if (ABF16) {
            const uint4* ap = (const uint4*)((const unsigned short*)Ap + (size_t)row * 128);
#pragma unroll
            for (int kc = 0; kc < 4; kc++)
                av[rt][kc] = rv ? ap[kc * 4 + quad] : make_uint4(0, 0, 0, 0);
        } else {
            const float4* ap = (const float4*)((const float*)Ap + (size_t)row * 128);
            float4 f[8];
#pragma unroll
            for (int kc = 0; kc < 4; kc++) {
                f[2 * kc]     = rv ? ap[kc * 8 + quad * 2]     : make_float4(0.f, 0.f, 0.f, 0.f);
                f[2 * kc + 1] = rv ? ap[kc * 8 + quad * 2 + 1] : make_float4(0.f, 0.f, 0.f, 0.f);
            }
#pragma unroll
            for (int kc = 0; kc < 4; kc++) {
                uint4 v;
                v.x = cvt_pk_bf16(f[2 * kc].x, f[2 * kc].y);
                v.y = cvt_pk_bf16(f[2 * kc].z, f[2 * kc].w);
                v.z = cvt_pk_bf16(f[2 * kc + 1].x, f[2 * kc + 1].y);
                v.w = cvt_pk_bf16(f[2 * kc + 1].z, f[2 * kc + 1].w);
                av[rt][kc] = v;
            }
        }
    }

    f32x4 acc[2][NT];
#pragma unroll
    for (int rt = 0; rt < 2; rt++)
#pragma unroll
        for (int ct = 0; ct < NT; ct++) acc[rt][ct] = (f32x4){0.f, 0.f, 0.f, 0.f};

#pragma unroll
    for (int kc = 0; kc < 4; kc++) {
        int kb = kc * 32 + quad * 8;
        bf16x8 afrag[2];
#pragma unroll
        for (int rt = 0; rt < 2; rt++) {
            if (MODE) {
                unsigned int uu[4] = {av[rt][kc].x, av[rt][kc].y, av[rt][kc].z, av[rt][kc].w};
                unsigned int* up = (unsigned int*)&afrag[rt];
#pragma unroll
                for (int i = 0; i < 4; i++) {
                    int k0 = kb + 2 * i;
                    float2 sa = sST[k0], sb = sST[k0 + 1];
                    float lo = fmaxf(bf_lo(uu[i]) * sa.x + sa.y, 0.f);
                    float hi = fmaxf(bf_hi(uu[i]) * sb.x + sb.y, 0.f);
                    up[i] = cvt_pk_bf16(lo, hi);
                }
            } else {
                afrag[rt] = *(bf16x8*)&av[rt][kc];
            }
        }
#pragma unroll
        for (int ct = 0; ct < NT; ct++) {
            bf16x8 bfrag = *(bf16x8*)&WtL[ct * 16 + m16][kb];
#pragma unroll
            for (int rt = 0; rt < 2; rt++)
                acc[rt][ct] = __builtin_amdgcn_mfma_f32_16x16x32_bf16(
                    afrag[rt], bfrag, acc[rt][ct], 0, 0, 0);
        }
    }

#pragma unroll
    for (int rt = 0; rt < 2; rt++)
#pragma unroll
        for (int r = 0; r < 4; r++) {
            int row = rbase + rt * 16 + quad * 4 + r;
            if (row < N_NODES) {
                float d = dinv[row];
#pragma unroll
                for (int ct = 0; ct < NT; ct++) {
                    int c = ct * 16 + m16;
                    if (c < ncols) {
                        float val = acc[rt][ct][r] * d;
                        if (OBF16)
                            ((unsigned short*)Outp)[(size_t)row * ostride + c] =
                                (unsigned short)cvt_pk_bf16(val, 0.f);
                        else
                            ((float*)Outp)[(size_t)row * ostride + c] = val;
                    }
                }
            }
        }
}

// ---------------- Aggregation: one wave per dst node, quarter-wave per record ----------------
// r0-proven gather loop (unroll-2, wave-uniform). Epilogue: cvt_pk bf16 pack + fused
// BN sum/sq stats (4KB LDS block reduce -> 256 atomics into 64-sliced partials).
// Grid covers exactly N_NODES (25000 blocks x 4 waves) -> no early return, barrier-safe.

__global__ __launch_bounds__(256) void agg_k(
    const unsigned int* __restrict__ H, const int2* __restrict__ rowse,
    const int* __restrict__ colv, const float* __restrict__ dinv,
    const float* __restrict__ bias,
    float* __restrict__ bnPS, float* __restrict__ bnPQ,
    unsigned int* __restrict__ out)
{
    __shared__ float red[2][4][16][8];   // 4 KB: [sum|sq][wave][c][k]

    int t = threadIdx.x;
    int gw = (blockIdx.x * 256 + t) >> 6;    // exact: 25000*4 == N_NODES
    int lane = t & 63;
    int w = t >> 6;
    int q = lane >> 4;             // quarter id: records 4t+q
    int c = lane & 15;             // uint4 index within row (channels 8c..8c+7)
    int2 se = rowse[gw];
    int rp = se.x, re = se.y;
    const uint4* H4 = (const uint4*)H;   // row = 16 uint4 (256 B)

    float a0 = 0.f, a1 = 0.f, a2 = 0.f, a3 = 0.f;
    float a4 = 0.f, a5 = 0.f, a6 = 0.f, a7 = 0.f;
    if (q == 0) {                  // self-loop (prescaled row)
        uint4 u = H4[(size_t)gw * 16 + c];
        a0 = bf_lo(u.x); a1 = bf_hi(u.x); a2 = bf_lo(u.y); a3 = bf_hi(u.y);
        a4 = bf_lo(u.z); a5 = bf_hi(u.z); a6 = bf_lo(u.w); a7 = bf_hi(u.w);
    }

    for (int j0 = rp; j0 < re; j0 += 64) {
        int idx = (j0 + lane < re) ? colv[j0 + lane] : 0;
        int n = min(64, re - j0);
        int nq = n >> 2;           // complete groups of 4 records
        int t4 = 0;
        for (; t4 + 1 < nq; t4 += 2) {
            int sa = __shfl(idx, 4 * t4 + q);
            int sb = __shfl(idx, 4 * t4 + 4 + q);
            uint4 ua = H4[(size_t)sa * 16 + c];
            uint4 ub = H4[(size_t)sb * 16 + c];
            a0 += bf_lo(ua.x) + bf_lo(ub.x);
            a1 += bf_hi(ua.x) + bf_hi(ub.x);
            a2 += bf_lo(ua.y) + bf_lo(ub.y);
            a3 += bf_hi(ua.y) + bf_hi(ub.y);
            a4 += bf_lo(ua.z) + bf_lo(ub.z);
            a5 += bf_hi(ua.z) + bf_hi(ub.z);
            a6 += bf_lo(ua.w) + bf_lo(ub.w);
            a7 += bf_hi(ua.w) + bf_hi(ub.w);
        }
        if (t4 < nq) {
            int sa = __shfl(idx, 4 * t4 + q);
            uint4 ua = H4[(size_t)sa * 16 + c];
            a0 += bf_lo(ua.x); a1 += bf_hi(ua.x);
            a2 += bf_lo(ua.y); a3 += bf_hi(ua.y);
            a4 += bf_lo(ua.z); a5 += bf_hi(ua.z);
            a6 += bf_lo(ua.w); a7 += bf_hi(ua.w);
        }
        int rem = n & 3;           // tail records: quarters 0..rem-1
        if (rem) {
            int sa = __shfl(idx, (n - rem) + q);
            if (q < rem) {
                uint4 ua = H4[(size_t)sa * 16 + c];
                a0 += bf_lo(ua.x); a1 += bf_hi(ua.x);
                a2 += bf_lo(ua.y); a3 += bf_hi(ua.y);
                a4 += bf_lo(ua.z); a5 += bf_hi(ua.z);
                a6 += bf_lo(ua.w); a7 += bf_hi(ua.w);
            }
        }
    }

    // combine the four quarter accumulators (full butterfly: all lanes get totals)
    a0 += __shfl_xor(a0, 16); a0 += __shfl_xor(a0, 32);
    a1 += __shfl_xor(a1, 16); a1 += __shfl_xor(a1, 32);
    a2 += __shfl_xor(a2, 16); a2 += __shfl_xor(a2, 32);
    a3 += __shfl_xor(a3, 16); a3 += __shfl_xor(a3, 32);
    a4 += __shfl_xor(a4, 16); a4 += __shfl_xor(a4, 32);
    a5 += __shfl_xor(a5, 16); a5 += __shfl_xor(a5, 32);
    a6 += __shfl_xor(a6, 16); a6 += __shfl_xor(a6, 32);
    a7 += __shfl_xor(a7, 16); a7 += __shfl_xor(a7, 32);

    if (q == 0) {
        float d = dinv[gw];
        float4 ba = ((const float4*)bias)[2 * c];
        float4 bb = ((const float4*)bias)[2 * c + 1];
        float vv[8];
        vv[0] = a0 * d + ba.x; vv[1] = a1 * d + ba.y;
        vv[2] = a2 * d + ba.z; vv[3] = a3 * d + ba.w;
        vv[4] = a4 * d + bb.x; vv[5] = a5 * d + bb.y;
        vv[6] = a6 * d + bb.z; vv[7] = a7 * d + bb.w;
        uint4 r;
        r.x = cvt_pk_bf16(vv[0], vv[1]);
        r.y = cvt_pk_bf16(vv[2], vv[3]);
        r.z = cvt_pk_bf16(vv[4], vv[5]);
        r.w = cvt_pk_bf16(vv[6], vv[7]);
        ((uint4*)out)[(size_t)gw * 16 + c] = r;
#pragma unroll
        for (int k = 0; k < 8; k++) {
            red[0][w][c][k] = vv[k];
            red[1][w][c][k] = vv[k] * vv[k];
        }
    }
    __syncthreads();

    // BN partials: 256 threads = {sum,sq} x 128 channels; one atomic each into 64-sliced array
    {
        int part = t >> 7;         // 0: sum, 1: sq
        int ch = t & 127;
        int cc = ch >> 3, k = ch & 7;
        float s = red[part][0][cc][k] + red[part][1][cc][k]
                + red[part][2][cc][k] + red[part][3][cc][k];
        atomicAdd((part ? bnPQ : bnPS) + (blockIdx.x & 63) * 128 + ch, s);
    }
}

// ---------------- Final aggregation (bf16 48-stride rows), quarter-wave + log_softmax ----------------

__global__ __launch_bounds__(256) void agg_out_k(
    const unsigned int* __restrict__ H, const int2* __restrict__ rowse,
    const int* __restrict__ colv, const float* __restrict__ dinv,
    const float* __restrict__ b2, float* __restrict__ out)
{
    int gw = (blockIdx.x * 256 + threadIdx.x) >> 6;
    int lane = threadIdx.x & 63;
    if (gw >= N_NODES) return;
    int q = lane >> 4;
    int c = lane & 15;
    bool ld = c < 12;              // 12 uint2 = 48 bf16 per row
    int2 se = rowse[gw];
    int rp = se.x, re = se.y;
    const uint2* H2 = (const uint2*)H;   // row = 12 uint2 (96 B)

    float a0 = 0.f, a1 = 0.f, a2 = 0.f, a3 = 0.f;
    if (q == 0 && ld) {
        uint2 u = H2[(size_t)gw * 12 + c];   // self (prescaled)
        a0 = bf_lo(u.x); a1 = bf_hi(u.x); a2 = bf_lo(u.y); a3 = bf_hi(u.y);
    }

    for (int j0 = rp; j0 < re; j0 += 64) {
        int idx = (j0 + lane < re) ? colv[j0 + lane] : 0;
        int n = min(64, re - j0);
        int nq = n >> 2;
        int t4 = 0;
        for (; t4 + 1 < nq; t4 += 2) {
            int sa = __shfl(idx, 4 * t4 + q);
            int sb = __shfl(idx, 4 * t4 + 4 + q);
            if (ld) {
                uint2 ua = H2[(size_t)sa * 12 + c];
                uint2 ub = H2[(size_t)sb * 12 + c];
                a0 += bf_lo(ua.x) + bf_lo(ub.x);
                a1 += bf_hi(ua.x) + bf_hi(ub.x);
                a2 += bf_lo(ua.y) + bf_lo(ub.y);
                a3 += bf_hi(ua.y) + bf_hi(ub.y);
            }
        }
        if (t4 < nq) {
            int sa = __shfl(idx, 4 * t4 + q);
            if (ld) {
                uint2 ua = H2[(size_t)sa * 12 + c];
                a0 += bf_lo(ua.x); a1 += bf_hi(ua.x);
                a2 += bf_lo(ua.y); a3 += bf_hi(ua.y);
            }
        }
        int rem = n & 3;
        if (rem) {
            int sa = __shfl(idx, (n - rem) + q);
            if (q < rem && ld) {
                uint2 ua = H2[(size_t)sa * 12 + c];
                a0 += bf_lo(ua.x); a1 += bf_hi(ua.x);
                a2 += bf_lo(ua.y); a3 += bf_hi(ua.y);
            }
        }
    }

    a0 += __shfl_xor(a0, 16); a0 += __shfl_xor(a0, 32);
    a1 += __shfl_xor(a1, 16); a1 += __shfl_xor(a1, 32);
    a2 += __shfl_xor(a2, 16); a2 += __shfl_xor(a2, 32);
    a3 += __shfl_xor(a3, 16); a3 += __shfl_xor(a3, 32);

    float d = dinv[gw];
    int ch = c * 4;
    float v0 = -INFINITY, v1 = -INFINITY, v2 = -INFINITY, v3 = -INFINITY;
    if (ld) {
        v0 = a0 * d + b2[ch];
        v1 = a1 * d + b2[ch + 1];
        v2 = a2 * d + b2[ch + 2];
        if (ch + 3 < OUTD) v3 = a3 * d + b2[ch + 3];
    }
    float m = fmaxf(fmaxf(v0, v1), fmaxf(v2, v3));
    m = fmaxf(m, __shfl_xor(m, 1));
    m = fmaxf(m, __shfl_xor(m, 2));
    m = fmaxf(m, __shfl_xor(m, 4));
    m = fmaxf(m, __shfl_xor(m, 8));
    float e = 0.f;
    if (ld) {
        e = __expf(v0 - m) + __expf(v1 - m) + __expf(v2 - m);
        if (ch + 3 < OUTD) e += __expf(v3 - m);
    }
    float sum = e;
    sum += __shfl_xor(sum, 1);
    sum += __shfl_xor(sum, 2);
    sum += __shfl_xor(sum, 4);
    sum += __shfl_xor(sum, 8);
    float ls = logf(sum);
    if (q == 0 && ld) {
        float* op = out + (size_t)gw * OUTD + ch;
        op[0] = v0 - m - ls;
        op[1] = v1 - m - ls;
        op[2] = v2 - m - ls;
        if (ch + 3 < OUTD) op[3] = v3 - m - ls;
    }
}

// ---------------- launch ----------------

extern "C" void kernel_launch(void* const* d_in, const int* in_sizes, int n_in,
                              void* d_out, int out_size, void* d_ws, size_t ws_size,
                              hipStream_t stream)
{
    const float* x   = (const float*)d_in[0];
    const int*   ei  = (const int*)d_in[1];
    const float* W0  = (const float*)d_in[2];
    const float* b0  = (const float*)d_in[3];
    const float* W1  = (const float*)d_in[4];
    const float* b1  = (const float*)d_in[5];
    const float* W2  = (const float*)d_in[6];
    const float* b2  = (const float*)d_in[7];
    const float* g0  = (const float*)d_in[8];
    const float* be0 = (const float*)d_in[9];
    const float* g1  = (const float*)d_in[10];
    const float* be1 = (const float*)d_in[11];
    const int* srcv = ei;
    const int* dstv = ei + N_EDGES;

    char* w = (char*)d_ws;
    unsigned int* H0 = (unsigned int*)w;  w += (size_t)N_NODES * 128 * 2;   // bf16 [N][128]
    unsigned int* H1 = (unsigned int*)w;  w += (size_t)N_NODES * 128 * 2;   // bf16 [N][128]
    unsigned int* Hf = (unsigned int*)w;  w += (size_t)N_NODES * OSTR * 2;  // bf16 [N][48]
    unsigned int* binned = (unsigned int*)w; w += (size_t)NB * BCAP * 4;    // 8.0 MB
    int* colv = (int*)w;        w += (size_t)NB * BCAP * 4;                 // 8.0 MB (fixed regions)
    unsigned short* Wt0 = (unsigned short*)w; w += 16384 * 2;
    unsigned short* Wt1 = (unsigned short*)w; w += 16384 * 2;
    unsigned short* Wt2 = (unsigned short*)w; w += 48 * 128 * 2;
    int2* rowse = (int2*)w;     w += (size_t)N_NODES * 8;
    float* dinv = (float*)w;    w += (size_t)N_NODES * 4;
    // single-memset region: gcur (784 ints) + 4 x 64-sliced BN partials (64*128 floats each)
    int* gcur = (int*)w;        w += 784 * 4;
    float* bnP0S = (float*)w;   w += 64 * 128 * 4;
    float* bnP0Q = (float*)w;   w += 64 * 128 * 4;
    float* bnP1S = (float*)w;   w += 64 * 128 * 4;
    float* bnP1Q = (float*)w;   w += 64 * 128 * 4;

    int gb = (N_NODES + 127) / 128;       // 782
    int ab = (N_NODES * 64 + 255) / 256;  // 25000 (exactly N_NODES waves)

    hipMemsetAsync(gcur, 0, 784 * 4 + 4 * 64 * 128 * 4, stream);

    binA_k<<<NCHB + CWB, 256, 0, stream>>>(srcv, dstv, gcur, binned,
                                           W0, W1, W2, Wt0, Wt1, Wt2);
    binB_k<<<NB, 256, 0, stream>>>(binned, gcur, rowse, dinv, colv);

    // Layer 0: x fp32 -> H0 bf16 (dinv-prescaled); agg fuses bias + BN stats
    gemm_k<0, 0, 8, 1><<<gb, 256, 0, stream>>>(x, Wt0, nullptr, nullptr, nullptr, nullptr,
                                               dinv, H0, 128, 128);
    agg_k<<<ab, 256, 0, stream>>>(H0, rowse, colv, dinv, b0, bnP0S, bnP0Q, H1);

    // Layer 1: BN-final+BN-apply+ReLU fused into gemm, bf16 MFMA
    gemm_k<1, 1, 8, 1><<<gb, 256, 0, stream>>>(H1, Wt1, bnP0S, bnP0Q, g0, be0,
                                               dinv, H0, 128, 128);
    agg_k<<<ab, 256, 0, stream>>>(H0, rowse, colv, dinv, b1, bnP1S, bnP1Q, H1);

    // Layer 2: 47-wide out (bf16, stride 48) + fused log_softmax aggregation
    gemm_k<1, 1, 3, 1><<<gb, 256, 0, stream>>>(H1, Wt2, bnP1S, bnP1Q, g1, be1,
                                               dinv, Hf, OUTD, OSTR);
    agg_out_k<<<ab, 256, 0, stream>>>(Hf, rowse, colv, dinv, b2, (float*)d_out);
}